// Round 1
// 240.042 us; speedup vs baseline: 1.1052x; 1.1052x over previous
//
#include <hip/hip_runtime.h>

#define NALGOS 64
#define NTASKS 1024
#define LXLEN  512
#define TOUT   (LXLEN + 1)   // 513
#define PROWS  (LXLEN + 8)   // 8 pad rows for phase1's t+8 prefetch overrun

__device__ __forceinline__ float rdlane(float v, int lane) {
    return __int_as_float(__builtin_amdgcn_readlane(__float_as_int(v), lane));
}

// ---------------------------------------------------------------------------
// Phase 0: materialize P[t][i] = tm[lx[t]][lx[i]] (512x512, 1 MB) with full
// parallelism so phase1's per-step loads become lane-coalesced. One block per
// row t; scattered 4B gathers here are amortized over 520 parallel blocks.
// ---------------------------------------------------------------------------
__global__ __launch_bounds__(256) void phase0_kernel(
    const int* __restrict__ lx, const float* __restrict__ tm,
    float* __restrict__ P)
{
    const int t = blockIdx.x;          // 0..PROWS-1
    const int i = threadIdx.x;
    if (t < LXLEN) {
        const int row = lx[t] * NTASKS;
        P[t * LXLEN + i]       = tm[row + lx[i]];
        P[t * LXLEN + i + 256] = tm[row + lx[i + 256]];
    } else {                            // pad rows: loaded by phase1, unused
        P[t * LXLEN + i]       = 0.f;
        P[t * LXLEN + i + 256] = 0.f;
    }
}

// ---------------------------------------------------------------------------
// Phase 1: per-algo scalar coefficient chain. One wave per algo, 64 blocks.
// Lane l, reg q holds V[i]=result[lx[i]] for i=q*64+l. Chain scalar via
// v_readlane; V-update/prefetch only future regs (k>=q); row refill now
// lane-coalesced from P. Serial-chain floor ~46 cyc/step.
// ---------------------------------------------------------------------------
__global__ __launch_bounds__(64) void phase1_kernel(
    const int*   __restrict__ lx,
    const float* __restrict__ P,
    const float* __restrict__ diff,
    const float* __restrict__ eff_g,
    const float* __restrict__ mem_g,
    const float* __restrict__ boost_g,
    float*       __restrict__ coef_out)
{
    const int a = blockIdx.x, lane = threadIdx.x;

    float nk[8]; float V[8];
    #pragma unroll
    for (int k = 0; k < 8; ++k) {
        const int tsk = lx[lane + 64 * k];
        nk[k] = -1.4426950408889634f / diff[tsk];
        V[k] = 0.f;
    }
    const float eff = eff_g[a], mem = mem_g[a], boost = boost_g[a];

    // prime 8-deep row pipeline: G[d][k] = P[d][64k+lane], d = 0..7
    float G[8][8];
    #pragma unroll
    for (int d = 0; d < 8; ++d)
        #pragma unroll
        for (int k = 0; k < 8; ++k)
            G[d][k] = P[d * LXLEN + 64 * k + lane];

    float coef = eff;
    float* cout = coef_out + (size_t)a * LXLEN;

    #pragma unroll
    for (int q = 0; q < 8; ++q) {
        float cbuf = 0.f;
        for (int g = 0; g < 8; ++g) {
            const int tb = q * 64 + g * 8;
            #pragma unroll
            for (int j = 0; j < 8; ++j) {
                // ---- serial chain ----
                const float p = V[q] * nk[q];
                float x = rdlane(p, g * 8 + j);       // V_{t-1}[t]*nk_t, uniform
                x = fminf(fmaxf(x, -126.f), 126.f);
                const float e = __builtin_exp2f(x);
                const float u = (1.f - e) * __builtin_amdgcn_rcpf(1.f + e);
                coef = __builtin_fmaf(u, boost, eff);
                cbuf = (lane == g * 8 + j) ? coef : cbuf;
                // ---- V update, future regs only ----
                #pragma unroll
                for (int k = q; k < 8; ++k)
                    V[k] = __builtin_fmaf(V[k], mem, G[j][k] * coef);
                // ---- refill row t+8, lane-coalesced ----
                const float* rp = P + (tb + j + 8) * LXLEN + lane;
                #pragma unroll
                for (int k = q; k < 8; ++k)
                    G[j][k] = rp[64 * k];
            }
        }
        cout[q * 64 + lane] = cbuf;                   // coalesced, 1/chunk
    }
}

// ---------------------------------------------------------------------------
// Phase 2: barrier-free bulk pass, t-chunked (contractive warmup, mem^128
// ~1e-12 << threshold). Grid = 64 algos x 4 t-chunks x 4 n-segs = 1024 blocks
// x 256 thr. NEW this round: 64-B-granule-ALIGNED stores. Rows start at
// row*2052+4k bytes, so fixed 64B bursts straddle dirty granules; with ~2MB
// of writes/round flowing through each 4MB XCD-L2, the partially-dirty
// granule is evicted before its second half arrives -> measured 1.92x HBM
// write amplification (259 MB vs 134.5 MB payload). Fix: per-thread 32-float
// circular buffer in LDS (runtime shift is fine in LDS), shifted by the
// row's phase phi=(n+1)&15 so that every flush is one FULL 64B granule,
// emitted as 4 back-to-back dwordx4 (granule fully dirty within a few
// instructions -> single clean eviction). Only the head/tail partials
// (shared with the neighboring c-chunk) remain split -> ~1.12x expected.
// ---------------------------------------------------------------------------
__global__ __launch_bounds__(256, 4) void phase2_kernel(
    const int*   __restrict__ lx,
    const float* __restrict__ tm,
    const float* __restrict__ diff,
    const float* __restrict__ mem_g,
    const float* __restrict__ coef,
    float*       __restrict__ out)
{
    const int b = blockIdx.x;
    const int a = b >> 4, c = (b >> 2) & 3;
    const int n = ((b & 3) << 8) | threadIdx.x;
    const int t_begin = (c == 0) ? 0 : (c - 1) * 128;
    const int warm    = (c == 0) ? 0 : 128;
    const int len     = warm + 128;

    __shared__ __align__(16) int   task_sh[272 + 16];
    __shared__ __align__(16) float coef_sh[272 + 16];
    // per-thread 32-float ring, stride 36 floats (144 B): keeps float4 LDS
    // reads 16B-aligned and staggers threads across banks (start bank 4*tid).
    __shared__ __align__(16) float ring[256 * 36];    // 36 KB

    for (int i = threadIdx.x; i < len + 16; i += 256) {
        const int t = t_begin + i;
        task_sh[i] = (t < LXLEN) ? lx[t] : 0;
        coef_sh[i] = (t < LXLEN) ? coef[a * LXLEN + t] : 0.f;
    }

    const float mem   = mem_g[a];
    const float negkd = -1.4426950408889634f / diff[n];
    float* outp = out + ((size_t)a * NTASKS + n) * TOUT;
    float r = 0.f;

    float* ringp = ring + threadIdx.x * 36;
    // chunk-local value v lives at global float index r*513 + c*128 + 1 + v;
    // (that index) mod 16 == ((n+1) + v) mod 16  ->  phase phi, head hp.
    const int phi = (n + 1) & 15;        // misalignment within 64B granule
    const int hp  = 16 - phi;            // head length, 1..16

    __syncthreads();

    float rbuf[16];
    #pragma unroll
    for (int j = 0; j < 16; ++j) {
        const int tk = __builtin_amdgcn_readfirstlane(task_sh[j]);
        rbuf[j] = tm[(size_t)tk * NTASKS + n];
    }

    // warmup: r-recurrence only (no sig, no store), rolling 16-row pipeline
    for (int base = 0; base < warm; base += 16) {
        float nbuf[16];
        #pragma unroll
        for (int j = 0; j < 16; ++j) {
            const int tk = __builtin_amdgcn_readfirstlane(task_sh[base + 16 + j]);
            nbuf[j] = tm[(size_t)tk * NTASKS + n];
        }
        #pragma unroll
        for (int v = 0; v < 4; ++v) {
            const float4 cq = *(const float4*)&coef_sh[base + 4 * v];
            r = __builtin_fmaf(r, mem, rbuf[4 * v + 0] * cq.x);
            r = __builtin_fmaf(r, mem, rbuf[4 * v + 1] * cq.y);
            r = __builtin_fmaf(r, mem, rbuf[4 * v + 2] * cq.z);
            r = __builtin_fmaf(r, mem, rbuf[4 * v + 3] * cq.w);
        }
        #pragma unroll
        for (int j = 0; j < 16; ++j) rbuf[j] = nbuf[j];
    }

    if (c == 0) outp[0] = 0.f;
    float* op = outp + t_begin + warm + 1;

    for (int base = warm; base < len; base += 16) {
        const int kk = (base - warm) >> 4;            // round 0..7
        float nbuf[16];
        #pragma unroll
        for (int j = 0; j < 16; ++j) {
            const int tk = __builtin_amdgcn_readfirstlane(task_sh[base + 16 + j]);
            nbuf[j] = tm[(size_t)tk * NTASKS + n];
        }
        float sb[16];
        #pragma unroll
        for (int v = 0; v < 4; ++v) {
            const float4 cq = *(const float4*)&coef_sh[base + 4 * v];
            const float cf[4] = { cq.x, cq.y, cq.z, cq.w };
            #pragma unroll
            for (int u = 0; u < 4; ++u) {
                const int j = 4 * v + u;
                r = __builtin_fmaf(r, mem, rbuf[j] * cf[u]);
                float x = r * negkd;
                x = fminf(fmaxf(x, -126.f), 126.f);
                const float e = __builtin_exp2f(x);
                sb[j] = (1.f - e) * __builtin_amdgcn_rcpf(1.f + e);
            }
        }
        // ring write shifted by phi: value v=16*kk+j -> slot (v+phi)&31, so
        // granule m occupies ring slots [16+16m, 32+16m) mod 32 (aligned).
        #pragma unroll
        for (int j = 0; j < 16; ++j)
            ringp[(16 * kk + phi + j) & 31] = sb[j];

        if (kk == 0) {
            // head partial: v in [0, hp) straight from registers (predicated)
            #pragma unroll
            for (int j = 0; j < 16; ++j)
                if (j < hp) op[j] = sb[j];
        } else {
            // flush granule m = kk-1: ring slots [16*kk, 16*kk+16) mod 32,
            // i.e. byte offset 64*(kk&1); global addr is 64B-aligned.
            const float* rq = ringp + ((16 * kk) & 31);
            const float4 q0 = ((const float4*)rq)[0];
            const float4 q1 = ((const float4*)rq)[1];
            const float4 q2 = ((const float4*)rq)[2];
            const float4 q3 = ((const float4*)rq)[3];
            float* dst = op + hp + (kk - 1) * 16;
            ((float4*)dst)[0] = q0;
            ((float4*)dst)[1] = q1;
            ((float4*)dst)[2] = q2;
            ((float4*)dst)[3] = q3;
        }
        #pragma unroll
        for (int j = 0; j < 16; ++j) rbuf[j] = nbuf[j];
    }

    // tail partial: v in [hp+112, 128) = ring slots [0, phi) (predicated)
    #pragma unroll
    for (int j = 0; j < 16; ++j)
        if (j < phi) op[hp + 112 + j] = ringp[j];
}

// ---------------------------------------------------------------------------
// Fallback (validated R1 kernel): used only if ws can't hold coef + P.
// ---------------------------------------------------------------------------
__global__ __launch_bounds__(1024) void fused_fallback_kernel(
    const int* __restrict__ lx, const float* __restrict__ tm,
    const float* __restrict__ diff, const float* __restrict__ eff_g,
    const float* __restrict__ mem_g, const float* __restrict__ boost_g,
    float* __restrict__ out)
{
    const int a = blockIdx.x, n = threadIdx.x;
    __shared__ int lx_sh[LXLEN];
    __shared__ float sbuf[2];
    if (n < LXLEN) lx_sh[n] = lx[n];
    if (n == 0) sbuf[0] = 0.0f;
    const float eff = eff_g[a], mem = mem_g[a], boost = boost_g[a];
    const float negkd = -1.4426950408889634f / diff[n];
    float* outp = out + ((size_t)a * NTASKS + n) * TOUT;
    outp[0] = 0.0f;
    float r = 0.0f;
    __syncthreads();
    for (int t = 0; t < LXLEN; ++t) {
        const int task = lx_sh[t];
        const float s = sbuf[t & 1];
        const float coef = __builtin_fmaf(s, boost, eff);
        const float row = tm[task * NTASKS + n];
        r = __builtin_fmaf(r, mem, row * coef);
        float x = r * negkd;
        x = fminf(fmaxf(x, -126.0f), 126.0f);
        const float e = __builtin_exp2f(x);
        const float sig = (1.0f - e) * __builtin_amdgcn_rcpf(1.0f + e);
        outp[t + 1] = sig;
        if (t + 1 < LXLEN && n == lx_sh[t + 1]) sbuf[(t + 1) & 1] = sig;
        __syncthreads();
    }
}

extern "C" void kernel_launch(void* const* d_in, const int* in_sizes, int n_in,
                              void* d_out, int out_size, void* d_ws, size_t ws_size,
                              hipStream_t stream) {
    const int*   lx    = (const int*)  d_in[0];
    const float* tm    = (const float*)d_in[1];
    const float* diff  = (const float*)d_in[2];
    const float* eff   = (const float*)d_in[3];
    const float* mem   = (const float*)d_in[4];
    const float* boost = (const float*)d_in[5];
    float* out = (float*)d_out;

    const size_t coef_elems = (size_t)NALGOS * LXLEN;
    const size_t P_elems    = (size_t)PROWS * LXLEN;
    const size_t need_bytes = (coef_elems + P_elems) * sizeof(float);

    if (ws_size >= need_bytes) {
        float* coef = (float*)d_ws;
        float* P    = coef + coef_elems;
        phase0_kernel<<<dim3(PROWS), dim3(256), 0, stream>>>(lx, tm, P);
        phase1_kernel<<<dim3(NALGOS), dim3(64), 0, stream>>>(
            lx, P, diff, eff, mem, boost, coef);
        phase2_kernel<<<dim3(NALGOS * 16), dim3(256), 0, stream>>>(
            lx, tm, diff, mem, coef, out);
    } else {
        fused_fallback_kernel<<<dim3(NALGOS), dim3(NTASKS), 0, stream>>>(
            lx, tm, diff, eff, mem, boost, out);
    }
}